// Round 1
// baseline (820.906 us; speedup 1.0000x reference)
//
#include <hip/hip_runtime.h>

typedef unsigned short u16;
typedef unsigned int u32;
typedef __bf16 bf16x8 __attribute__((ext_vector_type(8)));
typedef float f32x4 __attribute__((ext_vector_type(4)));

#define T_DIM 256
#define U_DIM 64
#define DJ 640
#define VOCAB 1024
#define LDA 40   // LDS leading dim in bf16 units (32 data + 8 pad -> 20 dwords)

// round-to-nearest-even float -> bf16 (values here are bounded; no NaN path needed)
__device__ __forceinline__ u16 f2bf(float f) {
    u32 x = __float_as_uint(f);
    x += 0x7fffu + ((x >> 16) & 1u);
    return (u16)(x >> 16);
}

// tanh(x) = 1 - 2/(exp(2x)+1); exact limits at +/-inf, ~1e-6 rel err via v_exp_f32
__device__ __forceinline__ float fast_tanh(float x) {
    float e = __expf(2.0f * x);
    return 1.0f - 2.0f / (e + 1.0f);
}

// W_out (640x1024 fp32, row-major) -> Wt (1024x640 bf16, [n][k])
__global__ __launch_bounds__(256) void convert_wout(const float* __restrict__ W,
                                                    u16* __restrict__ Wt) {
    int idx = blockIdx.x * 256 + threadIdx.x;  // 640*1024 threads total
    int k = idx >> 10;
    int n = idx & 1023;
    Wt[n * DJ + k] = f2bf(W[idx]);
}

// out[r, j] = bias[j] + sum_k X[r,k] * W[k,j]   (N fixed = 640, 4 rows/block)
__global__ __launch_bounds__(320) void proj_kernel(const float* __restrict__ X,
                                                   const float* __restrict__ W,
                                                   const float* __restrict__ bias,
                                                   float* __restrict__ out,
                                                   int K) {
    __shared__ float xs[4][DJ];
    int r0 = blockIdx.x * 4;
    for (int idx = threadIdx.x; idx < 4 * K; idx += 320) {
        int r = idx / K, k = idx - r * K;
        xs[r][k] = X[(size_t)(r0 + r) * K + k];
    }
    __syncthreads();
    for (int jj = threadIdx.x; jj < DJ; jj += 320) {
        float b = bias[jj];
        float a0 = b, a1 = b, a2 = b, a3 = b;
        for (int k = 0; k < K; k++) {
            float w = W[(size_t)k * DJ + jj];  // coalesced across jj
            a0 = fmaf(xs[0][k], w, a0);        // xs[.][k] is a broadcast (free)
            a1 = fmaf(xs[1][k], w, a1);
            a2 = fmaf(xs[2][k], w, a2);
            a3 = fmaf(xs[3][k], w, a3);
        }
        out[(size_t)(r0 + 0) * DJ + jj] = a0;
        out[(size_t)(r0 + 1) * DJ + jj] = a1;
        out[(size_t)(r0 + 2) * DJ + jj] = a2;
        out[(size_t)(r0 + 3) * DJ + jj] = a3;
    }
}

// Fused: A[m,k] = tanh(enc_proj[b,t,k] + pred_proj[b,u,k]) generated into LDS,
// C[m,n] = clamp(A @ Wt^T + b_out). Tile 128x128, 256 threads, 16x16x32 bf16 MFMA.
__global__ __launch_bounds__(256) void joint_kernel(const float* __restrict__ encp,
                                                    const float* __restrict__ predp,
                                                    const u16* __restrict__ Wt,
                                                    const float* __restrict__ b_out,
                                                    float* __restrict__ out) {
    __shared__ u16 As[128 * LDA];
    __shared__ u16 Bs[128 * LDA];

    int ntile = blockIdx.x & 7;   // 8 n-tiles of 128
    int mtile = blockIdx.x >> 3;  // 512 m-tiles of 128
    int row0 = mtile * 128;       // global row = (b*T + t)*U + u
    int bidx = row0 >> 14;        // / (T*U) = /16384
    int t0 = (row0 & 16383) >> 6; // / U ; block covers t0, t0+1 (x 64 u)
    int n0 = ntile * 128;

    int tid = threadIdx.x;
    int lane = tid & 63;
    int wave = tid >> 6;
    int wm = wave & 1;   // wave quadrant: rows wm*64.., cols wn*64..
    int wn = wave >> 1;
    int lm = lane & 15;
    int quad = lane >> 4;

    // A staging: thread -> (row am, k-half ak), 16 elements each
    int am = tid >> 1;
    int ak = (tid & 1) << 4;
    const float* encA = encp + (size_t)(bidx * T_DIM + t0 + (am >> 6)) * DJ + ak;
    const float* predA = predp + (size_t)(bidx * U_DIM + (am & 63)) * DJ + ak;
    u16* Asw = As + am * LDA + ak;

    // B staging: thread -> (n-row bn, k-half bk)
    int bn = tid >> 1;
    int bk = (tid & 1) << 4;
    const u16* WtB = Wt + (size_t)(n0 + bn) * DJ + bk;
    u16* Bsw = Bs + bn * LDA + bk;

    f32x4 acc[4][4];
#pragma unroll
    for (int i = 0; i < 4; i++)
#pragma unroll
        for (int j = 0; j < 4; j++) {
            acc[i][j][0] = 0.f; acc[i][j][1] = 0.f;
            acc[i][j][2] = 0.f; acc[i][j][3] = 0.f;
        }

    for (int k0 = 0; k0 < DJ; k0 += 32) {
        // ---- stage A: tanh(enc+pred) -> bf16 LDS
        const float4* pe = (const float4*)(encA + k0);
        const float4* pp = (const float4*)(predA + k0);
#pragma unroll
        for (int i = 0; i < 4; i++) {
            float4 e = pe[i];
            float4 p = pp[i];
            uint2 v;
            v.x = (u32)f2bf(fast_tanh(e.x + p.x)) | ((u32)f2bf(fast_tanh(e.y + p.y)) << 16);
            v.y = (u32)f2bf(fast_tanh(e.z + p.z)) | ((u32)f2bf(fast_tanh(e.w + p.w)) << 16);
            *(uint2*)(Asw + i * 4) = v;
        }
        // ---- stage B: copy 32 k of Wt rows (already [n][k] bf16)
        const u16* src = WtB + k0;
        uint4 w0 = *(const uint4*)src;
        uint4 w1 = *(const uint4*)(src + 8);
        *(uint4*)Bsw = w0;
        *(uint4*)(Bsw + 8) = w1;

        __syncthreads();

        bf16x8 af[4], bfr[4];
#pragma unroll
        for (int i = 0; i < 4; i++)
            af[i] = *(const bf16x8*)(As + (wm * 64 + i * 16 + lm) * LDA + quad * 8);
#pragma unroll
        for (int j = 0; j < 4; j++)
            bfr[j] = *(const bf16x8*)(Bs + (wn * 64 + j * 16 + lm) * LDA + quad * 8);
#pragma unroll
        for (int i = 0; i < 4; i++)
#pragma unroll
            for (int j = 0; j < 4; j++)
                acc[i][j] = __builtin_amdgcn_mfma_f32_16x16x32_bf16(af[i], bfr[j], acc[i][j], 0, 0, 0);

        __syncthreads();
    }

    // ---- epilogue: C/D layout col=lane&15, row=quad*4+reg
#pragma unroll
    for (int j = 0; j < 4; j++) {
        int gc = n0 + wn * 64 + j * 16 + lm;
        float bo = b_out[gc];
#pragma unroll
        for (int i = 0; i < 4; i++) {
            int gr = row0 + wm * 64 + i * 16 + quad * 4;
#pragma unroll
            for (int r = 0; r < 4; r++) {
                float v = acc[i][j][r] + bo;
                v = fminf(fmaxf(v, -15.0f), 15.0f);
                out[(size_t)(gr + r) * VOCAB + gc] = v;
            }
        }
    }
}

extern "C" void kernel_launch(void* const* d_in, const int* in_sizes, int n_in,
                              void* d_out, int out_size, void* d_ws, size_t ws_size,
                              hipStream_t stream) {
    const float* enc    = (const float*)d_in[0];  // (4,256,512)
    const float* pred   = (const float*)d_in[1];  // (4,64,640)
    const float* W_enc  = (const float*)d_in[2];  // (512,640)
    const float* b_enc  = (const float*)d_in[3];  // (640)
    const float* W_pred = (const float*)d_in[4];  // (640,640)
    const float* b_pred = (const float*)d_in[5];  // (640)
    const float* W_out  = (const float*)d_in[6];  // (640,1024)
    const float* b_out  = (const float*)d_in[7];  // (1024)
    float* out = (float*)d_out;                   // (4,256,64,1024) fp32

    float* enc_proj  = (float*)d_ws;              // 1024*640 fp32
    float* pred_proj = enc_proj + 1024 * DJ;      // 256*640 fp32
    u16*   Wt        = (u16*)(pred_proj + 256 * DJ);  // 1024*640 bf16

    convert_wout<<<dim3(2560), dim3(256), 0, stream>>>(W_out, Wt);
    proj_kernel<<<dim3(256), dim3(320), 0, stream>>>(enc, W_enc, b_enc, enc_proj, 512);
    proj_kernel<<<dim3(64), dim3(320), 0, stream>>>(pred, W_pred, b_pred, pred_proj, 640);
    joint_kernel<<<dim3(4096), dim3(256), 0, stream>>>(enc_proj, pred_proj, Wt, b_out, out);
}

// Round 2
// 519.428 us; speedup vs baseline: 1.5804x; 1.5804x over previous
//
#include <hip/hip_runtime.h>

typedef unsigned short u16;
typedef unsigned int u32;
typedef __bf16 bf16x8 __attribute__((ext_vector_type(8)));
typedef float f32x4 __attribute__((ext_vector_type(4)));

#define T_DIM 256
#define U_DIM 64
#define DJ 640
#define VOCAB 1024

typedef __attribute__((address_space(3))) u32 lds_u32;
typedef const __attribute__((address_space(1))) u32 glb_u32;

__device__ __forceinline__ u16 f2bf(float f) {
    u32 x = __float_as_uint(f);
    x += 0x7fffu + ((x >> 16) & 1u);
    return (u16)(x >> 16);
}

__device__ __forceinline__ float fast_tanh(float x) {
    float e = __expf(2.0f * x);
    return 1.0f - 2.0f / (e + 1.0f);
}

// W_out (640x1024 fp32) -> Wt (1024x640 bf16, [n][k])
__global__ __launch_bounds__(256) void convert_wout(const float* __restrict__ W,
                                                    u16* __restrict__ Wt) {
    int idx = blockIdx.x * 256 + threadIdx.x;
    int k = idx >> 10;
    int n = idx & 1023;
    Wt[n * DJ + k] = f2bf(W[idx]);
}

// out[r,j] = bias[j] + sum_k X[r,k]*W[k,j]; 4 rows x 128 cols per block, K compile-time
template <int K>
__global__ __launch_bounds__(128) void proj_kernel(const float* __restrict__ X,
                                                   const float* __restrict__ W,
                                                   const float* __restrict__ bias,
                                                   float* __restrict__ out) {
    __shared__ float xs[4][K];
    int r0 = blockIdx.x * 4;
    int jj = blockIdx.y * 128 + threadIdx.x;
    for (int idx = threadIdx.x; idx < 4 * K; idx += 128) {
        int r = idx / K, k = idx - r * K;
        xs[r][k] = X[(size_t)(r0 + r) * K + k];
    }
    __syncthreads();
    float b = bias[jj];
    float a0 = b, a1 = b, a2 = b, a3 = b;
#pragma unroll 8
    for (int k = 0; k < K; k++) {
        float w = W[(size_t)k * DJ + jj];
        a0 = fmaf(xs[0][k], w, a0);
        a1 = fmaf(xs[1][k], w, a1);
        a2 = fmaf(xs[2][k], w, a2);
        a3 = fmaf(xs[3][k], w, a3);
    }
    out[(size_t)(r0 + 0) * DJ + jj] = a0;
    out[(size_t)(r0 + 1) * DJ + jj] = a1;
    out[(size_t)(r0 + 2) * DJ + jj] = a2;
    out[(size_t)(r0 + 3) * DJ + jj] = a3;
}

// A[m][k] = bf16(tanh(encp[b,t,k] + predp[b,u,k])), m = ((b*T+t)*U+u), 8 elems/thread
__global__ __launch_bounds__(256) void tanh_kernel(const float* __restrict__ encp,
                                                   const float* __restrict__ predp,
                                                   u16* __restrict__ A) {
    int id = blockIdx.x * 256 + threadIdx.x;     // 65536*80 ids
    int m = id / 80;
    int c = id - m * 80;
    int koff = c * 8;
    int b = m >> 14, t = (m >> 6) & 255, u = m & 63;
    const float4* pe = (const float4*)(encp + (size_t)(b * T_DIM + t) * DJ + koff);
    const float4* pp = (const float4*)(predp + (size_t)(b * U_DIM + u) * DJ + koff);
    float4 e0 = pe[0], e1 = pe[1];
    float4 p0 = pp[0], p1 = pp[1];
    uint4 v;
    v.x = (u32)f2bf(fast_tanh(e0.x + p0.x)) | ((u32)f2bf(fast_tanh(e0.y + p0.y)) << 16);
    v.y = (u32)f2bf(fast_tanh(e0.z + p0.z)) | ((u32)f2bf(fast_tanh(e0.w + p0.w)) << 16);
    v.z = (u32)f2bf(fast_tanh(e1.x + p1.x)) | ((u32)f2bf(fast_tanh(e1.y + p1.y)) << 16);
    v.w = (u32)f2bf(fast_tanh(e1.z + p1.z)) | ((u32)f2bf(fast_tanh(e1.w + p1.w)) << 16);
    *(uint4*)(A + (size_t)id * 8) = v;
}

// m97-style bf16 GEMM: C[65536x1024] = A[65536x640] * Wt[1024x640]^T + bias, clamp.
// 128x128 tile, 256 threads, unpadded LDS [128][32], global_load_lds width=16.
__global__ __launch_bounds__(256) void gemm_kernel(const u16* __restrict__ A,
                                                   const u16* __restrict__ Wt,
                                                   const float* __restrict__ b_out,
                                                   float* __restrict__ out) {
    __shared__ u16 As[128 * 32];
    __shared__ u16 Bs[128 * 32];

    int ntile = blockIdx.x & 7;
    int mtile = blockIdx.x >> 3;
    int row0 = mtile * 128;
    int n0 = ntile * 128;

    int tid = threadIdx.x;
    int lane = tid & 63;
    int wave = tid >> 6;
    int wm = wave & 1;
    int wn = wave >> 1;
    int lm = lane & 15;
    int quad = lane >> 4;

    // staging: wave w, inst i covers rows i*64 + w*16 + (lane>>2), k-off (lane&3)*8
    int mA = wave * 16 + (lane >> 2);
    int kA = (lane & 3) * 8;
    const u16* gA0 = A + (size_t)(row0 + mA) * DJ + kA;
    const u16* gA1 = gA0 + (size_t)64 * DJ;
    const u16* gB0 = Wt + (size_t)(n0 + mA) * DJ + kA;
    const u16* gB1 = gB0 + (size_t)64 * DJ;
    u16* lA0 = As + wave * 16 * 32;   // wave-uniform; HW adds lane*16B
    u16* lA1 = As + (64 + wave * 16) * 32;
    u16* lB0 = Bs + wave * 16 * 32;
    u16* lB1 = Bs + (64 + wave * 16) * 32;

    f32x4 acc[4][4];
#pragma unroll
    for (int i = 0; i < 4; i++)
#pragma unroll
        for (int j = 0; j < 4; j++) {
            acc[i][j][0] = 0.f; acc[i][j][1] = 0.f;
            acc[i][j][2] = 0.f; acc[i][j][3] = 0.f;
        }

    for (int k0 = 0; k0 < DJ; k0 += 32) {
        __builtin_amdgcn_global_load_lds((glb_u32*)(gA0 + k0), (lds_u32*)lA0, 16, 0, 0);
        __builtin_amdgcn_global_load_lds((glb_u32*)(gA1 + k0), (lds_u32*)lA1, 16, 0, 0);
        __builtin_amdgcn_global_load_lds((glb_u32*)(gB0 + k0), (lds_u32*)lB0, 16, 0, 0);
        __builtin_amdgcn_global_load_lds((glb_u32*)(gB1 + k0), (lds_u32*)lB1, 16, 0, 0);
        __syncthreads();

        bf16x8 af[4], bfr[4];
#pragma unroll
        for (int i = 0; i < 4; i++)
            af[i] = *(const bf16x8*)(As + (wm * 64 + i * 16 + lm) * 32 + quad * 8);
#pragma unroll
        for (int j = 0; j < 4; j++)
            bfr[j] = *(const bf16x8*)(Bs + (wn * 64 + j * 16 + lm) * 32 + quad * 8);
#pragma unroll
        for (int i = 0; i < 4; i++)
#pragma unroll
            for (int j = 0; j < 4; j++)
                acc[i][j] = __builtin_amdgcn_mfma_f32_16x16x32_bf16(af[i], bfr[j], acc[i][j], 0, 0, 0);

        __syncthreads();
    }

#pragma unroll
    for (int j = 0; j < 4; j++) {
        int gc = n0 + wn * 64 + j * 16 + lm;
        float bo = b_out[gc];
#pragma unroll
        for (int i = 0; i < 4; i++) {
            int gr = row0 + wm * 64 + i * 16 + quad * 4;
#pragma unroll
            for (int r = 0; r < 4; r++) {
                float v = acc[i][j][r] + bo;
                v = fminf(fmaxf(v, -15.0f), 15.0f);
                out[(size_t)(gr + r) * VOCAB + gc] = v;
            }
        }
    }
}

// ---------------- fallback (round-1 fused kernel) if ws too small ----------------
#define LDA 40
__global__ __launch_bounds__(256) void joint_fused(const float* __restrict__ encp,
                                                   const float* __restrict__ predp,
                                                   const u16* __restrict__ Wt,
                                                   const float* __restrict__ b_out,
                                                   float* __restrict__ out) {
    __shared__ u16 As[128 * LDA];
    __shared__ u16 Bs[128 * LDA];
    int ntile = blockIdx.x & 7;
    int mtile = blockIdx.x >> 3;
    int row0 = mtile * 128;
    int bidx = row0 >> 14;
    int t0 = (row0 & 16383) >> 6;
    int n0 = ntile * 128;
    int tid = threadIdx.x, lane = tid & 63, wave = tid >> 6;
    int wm = wave & 1, wn = wave >> 1, lm = lane & 15, quad = lane >> 4;
    int am = tid >> 1, ak = (tid & 1) << 4;
    const float* encA = encp + (size_t)(bidx * T_DIM + t0 + (am >> 6)) * DJ + ak;
    const float* predA = predp + (size_t)(bidx * U_DIM + (am & 63)) * DJ + ak;
    u16* Asw = As + am * LDA + ak;
    int bn = tid >> 1, bk = (tid & 1) << 4;
    const u16* WtB = Wt + (size_t)(n0 + bn) * DJ + bk;
    u16* Bsw = Bs + bn * LDA + bk;
    f32x4 acc[4][4];
#pragma unroll
    for (int i = 0; i < 4; i++)
#pragma unroll
        for (int j = 0; j < 4; j++) {
            acc[i][j][0] = 0.f; acc[i][j][1] = 0.f; acc[i][j][2] = 0.f; acc[i][j][3] = 0.f;
        }
    for (int k0 = 0; k0 < DJ; k0 += 32) {
        const float4* pe = (const float4*)(encA + k0);
        const float4* pp = (const float4*)(predA + k0);
#pragma unroll
        for (int i = 0; i < 4; i++) {
            float4 e = pe[i]; float4 p = pp[i];
            uint2 v;
            v.x = (u32)f2bf(fast_tanh(e.x + p.x)) | ((u32)f2bf(fast_tanh(e.y + p.y)) << 16);
            v.y = (u32)f2bf(fast_tanh(e.z + p.z)) | ((u32)f2bf(fast_tanh(e.w + p.w)) << 16);
            *(uint2*)(Asw + i * 4) = v;
        }
        const u16* src = WtB + k0;
        uint4 w0 = *(const uint4*)src;
        uint4 w1 = *(const uint4*)(src + 8);
        *(uint4*)Bsw = w0;
        *(uint4*)(Bsw + 8) = w1;
        __syncthreads();
        bf16x8 af[4], bfr[4];
#pragma unroll
        for (int i = 0; i < 4; i++)
            af[i] = *(const bf16x8*)(As + (wm * 64 + i * 16 + lm) * LDA + quad * 8);
#pragma unroll
        for (int j = 0; j < 4; j++)
            bfr[j] = *(const bf16x8*)(Bs + (wn * 64 + j * 16 + lm) * LDA + quad * 8);
#pragma unroll
        for (int i = 0; i < 4; i++)
#pragma unroll
            for (int j = 0; j < 4; j++)
                acc[i][j] = __builtin_amdgcn_mfma_f32_16x16x32_bf16(af[i], bfr[j], acc[i][j], 0, 0, 0);
        __syncthreads();
    }
#pragma unroll
    for (int j = 0; j < 4; j++) {
        int gc = n0 + wn * 64 + j * 16 + lm;
        float bo = b_out[gc];
#pragma unroll
        for (int i = 0; i < 4; i++) {
            int gr = row0 + wm * 64 + i * 16 + quad * 4;
#pragma unroll
            for (int r = 0; r < 4; r++) {
                float v = acc[i][j][r] + bo;
                v = fminf(fmaxf(v, -15.0f), 15.0f);
                out[(size_t)(gr + r) * VOCAB + gc] = v;
            }
        }
    }
}

extern "C" void kernel_launch(void* const* d_in, const int* in_sizes, int n_in,
                              void* d_out, int out_size, void* d_ws, size_t ws_size,
                              hipStream_t stream) {
    const float* enc    = (const float*)d_in[0];
    const float* pred   = (const float*)d_in[1];
    const float* W_enc  = (const float*)d_in[2];
    const float* b_enc  = (const float*)d_in[3];
    const float* W_pred = (const float*)d_in[4];
    const float* b_pred = (const float*)d_in[5];
    const float* W_out  = (const float*)d_in[6];
    const float* b_out  = (const float*)d_in[7];
    float* out = (float*)d_out;

    float* enc_proj  = (float*)d_ws;                     // 1024*640 f32
    float* pred_proj = enc_proj + 1024 * DJ;             // 256*640 f32
    u16*   Wt        = (u16*)(pred_proj + 256 * DJ);     // 1024*640 bf16
    u16*   Abuf      = Wt + 1024 * DJ;                   // 65536*640 bf16

    size_t need = (size_t)(1024 + 256) * DJ * 4 + (size_t)1024 * DJ * 2
                + (size_t)65536 * DJ * 2;

    convert_wout<<<dim3(2560), dim3(256), 0, stream>>>(W_out, Wt);
    proj_kernel<512><<<dim3(256, 5), dim3(128), 0, stream>>>(enc, W_enc, b_enc, enc_proj);
    proj_kernel<640><<<dim3(64, 5), dim3(128), 0, stream>>>(pred, W_pred, b_pred, pred_proj);

    if (ws_size >= need) {
        tanh_kernel<<<dim3(65536 * 80 / 256), dim3(256), 0, stream>>>(enc_proj, pred_proj, Abuf);
        gemm_kernel<<<dim3(4096), dim3(256), 0, stream>>>(Abuf, Wt, b_out, out);
    } else {
        joint_fused<<<dim3(4096), dim3(256), 0, stream>>>(enc_proj, pred_proj, Wt, b_out, out);
    }
}